// Round 1
// baseline (1047.957 us; speedup 1.0000x reference)
//
#include <hip/hip_runtime.h>
#include <math.h>

#define TS      64    // tile rows per block-iteration
#define LSTRIDE 68    // LDS row stride in floats: 68*4=272 B, 16B-aligned, optimal 8-phase b128
#define NQ      128   // total queries (32*4)
#define D       64    // feature dim

// Each block: 4 waves. Wave w owns queries [w*32, w*32+32). Each lane owns one
// row of the 64-row LDS tile. Query loads are wave-uniform -> s_load (scalar K$),
// so the inner loop is a pure v_fma_f32 stream with 4 accumulator chains.
__global__ __launch_bounds__(256, 2)
void score_kernel(const float* __restrict__ pred,
                  const float* __restrict__ acts,
                  unsigned long long* __restrict__ best,
                  int ntiles)
{
    __shared__ float lds[TS * LSTRIDE];
    const int tid   = threadIdx.x;
    const int lane  = tid & 63;
    const int wv    = __builtin_amdgcn_readfirstlane(tid >> 6);
    const int qbase = wv * 32;

    float bsim[32];
    int   bidx[32];
#pragma unroll
    for (int i = 0; i < 32; ++i) { bsim[i] = -3.0e38f; bidx[i] = 0; }

    for (int tile = blockIdx.x; tile < ntiles; tile += gridDim.x) {
        // ---- stage 64 rows x 64 floats (16 KB) into LDS, coalesced float4 ----
        const float4* src = (const float4*)(acts + (size_t)tile * (TS * D));
#pragma unroll
        for (int i = 0; i < 4; ++i) {
            int c   = tid + i * 256;        // chunk id 0..1023
            int r   = c >> 4;
            int col = c & 15;
            float4 v = src[c];
            *(float4*)&lds[r * LSTRIDE + col * 4] = v;
        }
        __syncthreads();

        // ---- lane's row -> 16 float4 registers ----
        float4 rv[16];
#pragma unroll
        for (int c = 0; c < 16; ++c)
            rv[c] = *(const float4*)&lds[lane * LSTRIDE + c * 4];

        float na2 = 0.f;
#pragma unroll
        for (int c = 0; c < 16; ++c) {
            na2 = fmaf(rv[c].x, rv[c].x, na2);
            na2 = fmaf(rv[c].y, rv[c].y, na2);
            na2 = fmaf(rv[c].z, rv[c].z, na2);
            na2 = fmaf(rv[c].w, rv[c].w, na2);
        }
        const float rna    = 1.0f / sqrtf(na2);   // nb[q] > 0 constant per q: drop it
        const int   rowidx = tile * TS + lane;

#pragma unroll
        for (int q = 0; q < 32; ++q) {
            const float4* P = (const float4*)(pred + (size_t)(qbase + q) * D);
            float a0 = 0.f, a1 = 0.f, a2 = 0.f, a3 = 0.f;
#pragma unroll
            for (int c = 0; c < 16; c += 4) {
                float4 p0 = P[c + 0], p1 = P[c + 1], p2 = P[c + 2], p3 = P[c + 3];
                a0 = fmaf(rv[c + 0].x, p0.x, a0);
                a0 = fmaf(rv[c + 0].y, p0.y, a0);
                a0 = fmaf(rv[c + 0].z, p0.z, a0);
                a0 = fmaf(rv[c + 0].w, p0.w, a0);
                a1 = fmaf(rv[c + 1].x, p1.x, a1);
                a1 = fmaf(rv[c + 1].y, p1.y, a1);
                a1 = fmaf(rv[c + 1].z, p1.z, a1);
                a1 = fmaf(rv[c + 1].w, p1.w, a1);
                a2 = fmaf(rv[c + 2].x, p2.x, a2);
                a2 = fmaf(rv[c + 2].y, p2.y, a2);
                a2 = fmaf(rv[c + 2].z, p2.z, a2);
                a2 = fmaf(rv[c + 2].w, p2.w, a2);
                a3 = fmaf(rv[c + 3].x, p3.x, a3);
                a3 = fmaf(rv[c + 3].y, p3.y, a3);
                a3 = fmaf(rv[c + 3].z, p3.z, a3);
                a3 = fmaf(rv[c + 3].w, p3.w, a3);
            }
            float dot = (a0 + a1) + (a2 + a3);
            float sim = dot * rna;
            if (sim > bsim[q]) { bsim[q] = sim; bidx[q] = rowidx; }
        }
        __syncthreads();
    }

    // ---- wave reduce (max sim, tie -> lowest idx) then device atomic merge ----
#pragma unroll
    for (int q = 0; q < 32; ++q) {
        unsigned u = __float_as_uint(bsim[q]);
        u = (u & 0x80000000u) ? ~u : (u | 0x80000000u);   // order-preserving float->uint
        unsigned long long key =
            ((unsigned long long)u << 32) | (unsigned)(~bidx[q]);
#pragma unroll
        for (int off = 32; off > 0; off >>= 1) {
            unsigned long long o = __shfl_xor(key, off, 64);
            if (o > key) key = o;
        }
        if (lane == 0) atomicMax(&best[qbase + q], key);
    }
}

__global__ void init_best(unsigned long long* best)
{
    if (threadIdx.x < NQ) best[threadIdx.x] = 0ull;
}

__global__ void gather_kernel(const unsigned long long* __restrict__ best,
                              const float* __restrict__ acts,
                              float* __restrict__ out)
{
    int t = blockIdx.x * 256 + threadIdx.x;   // 0..8191
    int q = t >> 6;
    int d = t & 63;
    unsigned idx = ~(unsigned)(best[q] & 0xffffffffull);
    out[t] = acts[(size_t)idx * D + d];
}

extern "C" void kernel_launch(void* const* d_in, const int* in_sizes, int n_in,
                              void* d_out, int out_size, void* d_ws, size_t ws_size,
                              hipStream_t stream)
{
    const float* pred = (const float*)d_in[0];   // (32,4,64)
    const float* acts = (const float*)d_in[1];   // (1000000,64)
    long n0 = in_sizes[0], n1 = in_sizes[1];
    if (n0 > n1) {                                // defensive: ensure acts is the big one
        const float* t = pred; pred = acts; acts = t;
        long tt = n0; n0 = n1; n1 = tt;
    }
    const int N      = (int)(n1 / D);
    const int ntiles = N / TS;                    // N = 1e6 = 15625 * 64 exactly

    unsigned long long* best = (unsigned long long*)d_ws;
    float* out = (float*)d_out;

    init_best<<<dim3(1), dim3(128), 0, stream>>>(best);
    score_kernel<<<dim3(1024), dim3(256), 0, stream>>>(pred, acts, best, ntiles);
    gather_kernel<<<dim3((NQ * D) / 256), dim3(256), 0, stream>>>(best, acts, out);
}

// Round 2
// 386.271 us; speedup vs baseline: 2.7130x; 2.7130x over previous
//
#include <hip/hip_runtime.h>
#include <hip/hip_bf16.h>
#include <math.h>

#define D        64      // feature dim
#define NQ       128     // 32*4 queries
#define TS       64      // action rows per tile
#define ASTRIDE  72      // bf16 elems per LDS row: 144 B, 16B-aligned, 2-way-max bank alias
#define MARGIN   0.025f  // > 2*eps_bf16 (covers RNE or truncating cvt) in cosine units
#define MAXTILES 15648   // >= 1e6/64 = 15625
#define CAP      128     // max flagged tiles per query

typedef __attribute__((ext_vector_type(8))) short  short8;
typedef __attribute__((ext_vector_type(4))) short  short4v;
typedef __attribute__((ext_vector_type(4))) float  f32x4;

__device__ inline unsigned ordf(float f) {
    unsigned u = __float_as_uint(f);
    return (u & 0x80000000u) ? ~u : (u | 0x80000000u);
}

__device__ inline short bf16bits(float f) {
    __hip_bfloat16 h = __float2bfloat16(f);
    return *(short*)&h;
}

__device__ inline short8 cvt8(f32x4 a, f32x4 b, float s) {
    short8 r;
    r[0] = bf16bits(a.x * s); r[1] = bf16bits(a.y * s);
    r[2] = bf16bits(a.z * s); r[3] = bf16bits(a.w * s);
    r[4] = bf16bits(b.x * s); r[5] = bf16bits(b.y * s);
    r[6] = bf16bits(b.z * s); r[7] = bf16bits(b.w * s);
    return r;
}

// K1: approx cosine sims via bf16 MFMA; emits per-(tile,query) max only.
// B-frags (queries, scaled by 1/||p||) live in registers for the whole kernel.
__global__ __launch_bounds__(256, 2)
void k1_score(const float* __restrict__ pred,
              const float* __restrict__ acts,
              float* __restrict__ tmax,
              int ntiles)
{
    __shared__ unsigned short As[TS * ASTRIDE];  // bf16 bit patterns
    __shared__ float rna[TS];                    // 1/||row||

    const int tid  = threadIdx.x;
    const int lane = tid & 63;
    const int wv   = tid >> 6;      // 0..3: wave owns queries [32w,32w+32)
    const int quad = lane >> 4;     // 0..3
    const int l15  = lane & 15;

    // ---- build B fragments once: q = 32w + nt*16 + l15, k-slice = ks*32+quad*8 ----
    short8 bfrag[2][2];
#pragma unroll
    for (int nt = 0; nt < 2; ++nt) {
        const int q = wv * 32 + nt * 16 + l15;
        const float* P = pred + q * D + quad * 8;
        f32x4 v0 = *(const f32x4*)(P);
        f32x4 v1 = *(const f32x4*)(P + 4);
        f32x4 v2 = *(const f32x4*)(P + 32);
        f32x4 v3 = *(const f32x4*)(P + 36);
        float nb2 = v0.x*v0.x + v0.y*v0.y + v0.z*v0.z + v0.w*v0.w
                  + v1.x*v1.x + v1.y*v1.y + v1.z*v1.z + v1.w*v1.w
                  + v2.x*v2.x + v2.y*v2.y + v2.z*v2.z + v2.w*v2.w
                  + v3.x*v3.x + v3.y*v3.y + v3.z*v3.z + v3.w*v3.w;
        // quads of same l15 hold disjoint k-slices of the same q: sum them
        nb2 += __shfl_xor(nb2, 16);
        nb2 += __shfl_xor(nb2, 32);
        const float rnb = 1.0f / sqrtf(nb2);
        bfrag[nt][0] = cvt8(v0, v1, rnb);   // ks=0
        bfrag[nt][1] = cvt8(v2, v3, rnb);   // ks=1
    }

    for (int tile = blockIdx.x; tile < ntiles; tile += gridDim.x) {
        // ---- stage: 64 rows x 64 fp32 -> bf16 LDS; norms via 16-lane shuffle ----
        const f32x4* src = (const f32x4*)(acts + (size_t)tile * (TS * D));
#pragma unroll
        for (int i = 0; i < 4; ++i) {
            int c  = tid + i * 256;     // float4 chunk 0..1023
            int r  = c >> 4;
            int c4 = c & 15;
            f32x4 v = src[c];
            float s = v.x*v.x + v.y*v.y + v.z*v.z + v.w*v.w;
            s += __shfl_xor(s, 1); s += __shfl_xor(s, 2);
            s += __shfl_xor(s, 4); s += __shfl_xor(s, 8);
            if ((tid & 15) == 0) rna[r] = 1.0f / sqrtf(s);
            short4v b;
            b[0] = bf16bits(v.x); b[1] = bf16bits(v.y);
            b[2] = bf16bits(v.z); b[3] = bf16bits(v.w);
            *(short4v*)&As[r * ASTRIDE + c4 * 4] = b;
        }
        __syncthreads();

        // ---- MFMA: 4 M-tiles x 2 N-tiles x 2 K-steps ----
        f32x4 acc[4][2];
#pragma unroll
        for (int mt = 0; mt < 4; ++mt)
#pragma unroll
            for (int nt = 0; nt < 2; ++nt)
                acc[mt][nt] = (f32x4){0.f, 0.f, 0.f, 0.f};

#pragma unroll
        for (int mt = 0; mt < 4; ++mt) {
            const int row = mt * 16 + l15;
            short8 a0 = *(const short8*)&As[row * ASTRIDE + quad * 8];       // ks=0
            short8 a1 = *(const short8*)&As[row * ASTRIDE + 32 + quad * 8];  // ks=1
#pragma unroll
            for (int nt = 0; nt < 2; ++nt) {
                acc[mt][nt] = __builtin_amdgcn_mfma_f32_16x16x32_bf16(a0, bfrag[nt][0], acc[mt][nt], 0, 0, 0);
                acc[mt][nt] = __builtin_amdgcn_mfma_f32_16x16x32_bf16(a1, bfrag[nt][1], acc[mt][nt], 0, 0, 0);
            }
        }

        // ---- epilogue: scale by rna, per-lane max over 16 rows, quad-reduce ----
        float m0 = -3.0e38f, m1 = -3.0e38f;
#pragma unroll
        for (int mt = 0; mt < 4; ++mt) {
            f32x4 r4 = *(const f32x4*)&rna[mt * 16 + quad * 4];  // broadcast within quad
            m0 = fmaxf(m0, acc[mt][0].x * r4.x); m1 = fmaxf(m1, acc[mt][1].x * r4.x);
            m0 = fmaxf(m0, acc[mt][0].y * r4.y); m1 = fmaxf(m1, acc[mt][1].y * r4.y);
            m0 = fmaxf(m0, acc[mt][0].z * r4.z); m1 = fmaxf(m1, acc[mt][1].z * r4.z);
            m0 = fmaxf(m0, acc[mt][0].w * r4.w); m1 = fmaxf(m1, acc[mt][1].w * r4.w);
        }
        m0 = fmaxf(m0, __shfl_xor(m0, 16)); m0 = fmaxf(m0, __shfl_xor(m0, 32));
        m1 = fmaxf(m1, __shfl_xor(m1, 16)); m1 = fmaxf(m1, __shfl_xor(m1, 32));
        if (lane < 32) {
            int nt = lane >> 4;
            tmax[(size_t)tile * NQ + wv * 32 + nt * 16 + (lane & 15)] = nt ? m1 : m0;
        }
        __syncthreads();
    }
}

// K2: one block per query. Find global approx max over tile-maxes, flag tiles
// within MARGIN (provably contains the exact argmax), exact fp32 rescore.
__global__ __launch_bounds__(256, 1)
void k2_rescore(const float* __restrict__ pred,
                const float* __restrict__ acts,
                const float* __restrict__ tmax,
                float* __restrict__ out,
                int ntiles)
{
    __shared__ float col[MAXTILES];
    __shared__ float wmax[4];
    __shared__ int   cnt;
    __shared__ int   list[CAP];

    const int q   = blockIdx.x;
    const int tid = threadIdx.x;

    float m = -3.0e38f;
    for (int t = tid; t < ntiles; t += 256) {
        float v = tmax[(size_t)t * NQ + q];
        col[t] = v;
        m = fmaxf(m, v);
    }
#pragma unroll
    for (int off = 1; off < 64; off <<= 1)
        m = fmaxf(m, __shfl_xor(m, off));
    if ((tid & 63) == 0) wmax[tid >> 6] = m;
    if (tid == 0) cnt = 0;
    __syncthreads();
    m = fmaxf(fmaxf(wmax[0], wmax[1]), fmaxf(wmax[2], wmax[3]));
    const float thr = m - MARGIN;

    for (int t = tid; t < ntiles; t += 256) {
        if (col[t] >= thr) {
            int i = atomicAdd(&cnt, 1);
            if (i < CAP) list[i] = t;
        }
    }
    __syncthreads();
    const int n = min(cnt, CAP);

    if (tid < 64) {   // wave 0: 64 lanes = 64 rows per flagged tile
        const f32x4* P = (const f32x4*)(pred + q * D);
        unsigned long long best = 0ull;
        for (int i = 0; i < n; ++i) {
            const int row = list[i] * TS + tid;
            const f32x4* A = (const f32x4*)(acts + (size_t)row * D);
            float dot = 0.f, na2 = 0.f;
#pragma unroll
            for (int c = 0; c < 16; ++c) {
                f32x4 a = A[c];
                f32x4 p = P[c];
                dot = fmaf(a.x, p.x, dot); na2 = fmaf(a.x, a.x, na2);
                dot = fmaf(a.y, p.y, dot); na2 = fmaf(a.y, a.y, na2);
                dot = fmaf(a.z, p.z, dot); na2 = fmaf(a.z, a.z, na2);
                dot = fmaf(a.w, p.w, dot); na2 = fmaf(a.w, a.w, na2);
            }
            float sim = dot * (1.0f / sqrtf(na2));
            unsigned long long key =
                ((unsigned long long)ordf(sim) << 32) | (unsigned)(~row);
#pragma unroll
            for (int off = 1; off < 64; off <<= 1) {
                unsigned long long o = __shfl_xor(key, off);
                if (o > key) key = o;
            }
            if (key > best) best = key;
        }
        const unsigned idx = ~(unsigned)(best & 0xffffffffull);
        out[q * D + tid] = acts[(size_t)idx * D + tid];
    }
}

extern "C" void kernel_launch(void* const* d_in, const int* in_sizes, int n_in,
                              void* d_out, int out_size, void* d_ws, size_t ws_size,
                              hipStream_t stream)
{
    const float* pred = (const float*)d_in[0];   // (32,4,64)
    const float* acts = (const float*)d_in[1];   // (1000000,64)
    long n0 = in_sizes[0], n1 = in_sizes[1];
    if (n0 > n1) {                                // defensive: acts is the big one
        const float* t = pred; pred = acts; acts = t;
        long tt = n0; n0 = n1; n1 = tt;
    }
    const int N      = (int)(n1 / D);
    const int ntiles = N / TS;                    // 1e6/64 = 15625

    float* tmax = (float*)d_ws;                   // ntiles*128*4 = 8 MB scratch
    float* out  = (float*)d_out;

    k1_score<<<dim3(1024), dim3(256), 0, stream>>>(pred, acts, tmax, ntiles);
    k2_rescore<<<dim3(NQ), dim3(256), 0, stream>>>(pred, acts, tmax, out, ntiles);
}